// Round 9
// baseline (336.680 us; speedup 1.0000x reference)
//
#include <hip/hip_runtime.h>

// iRPE contextual/transposed PRODUCT:
//   lt[b,h,i,k] = sum_d x[b,h,i,d] * W[h,d,k]   (K=49 GEMV per row)
//   out[b,h,i,j] = lt[b,h,i, bucket[i,j]]        (the 256 MB write)
//
// Round-9: kill the one-generation phase serialization. r5's grid (2048
// blocks = 8/CU) is a single generation: all blocks did GEMV (~30 us,
// store pipe idle) then stores (~57 us, compute idle). This version fuses
// per-plane: compute lt for one (bh,i) row, immediately NT-store its 4 KB,
// repeat x32 -- barrier-free, stores pipeline with compute from ~500 cyc in.
// W is pre-transposed into d_ws (Wt[h][k][d]) so lane k reads 16 coalesced
// float4s; the x row goes through a readfirstlane-forced uniform pointer
// (scalar loads). gid->i map, NT stores, plane-strided walk: r5 verbatim.

constexpr int cL = 1024;
constexpr int cD = 64;
constexpr int cK = 49;

typedef float vf4 __attribute__((ext_vector_type(4)));

__global__ void transpose_w(const float* __restrict__ W, float* __restrict__ Wt) {
    // 392 blocks x 64 threads: block = (h,k), thread = d
    const int hk = blockIdx.x;
    const int d  = threadIdx.x;
    const int h  = hk / cK;
    const int k  = hk - h * cK;
    Wt[(size_t)hk * cD + d] = W[((size_t)h * cD + d) * cK + k];
}

__global__ __launch_bounds__(256) void irpe_fused(
    const float* __restrict__ x,       // (B,H,L,D) = (bh, i, d)
    const float* __restrict__ Wt,      // (H,K,D) transposed, in d_ws
    const int*   __restrict__ bucket,  // (L,L), values in [0,49)
    float*       __restrict__ out)     // (B,H,L,L)
{
    __shared__ float sc[4][64];        // per-wave lt scratch, 1 KB

    // r5's winning map: CU-resident blocks cover all 8 residues of i mod 8.
    const int gid  = blockIdx.x;
    const int i_lo = gid >> 8;            // 0..7
    const int rest = gid & 255;
    const int i_hi = rest >> 1;           // 0..127
    const int half = gid & 1;
    const int i    = i_hi * 8 + i_lo;     // 0..1023
    const int bh0  = half * 32;
    const int tid  = threadIdx.x;
    const int lane = tid & 63;
    const int w    = tid >> 6;

    const int kc = lane < cK ? lane : (cK - 1);
    const int4* brow = (const int4*)(bucket + (size_t)i * cL);

    for (int q = 0; q < 8; ++q) {
        const int lh = q * 4 + w;          // wave w owns planes w, w+4, ...
        const int bh = bh0 + lh;
        const int h  = bh & 7;

        // x row: wave-uniform scalar pointer (readfirstlane forces SGPR)
        const int xoff = __builtin_amdgcn_readfirstlane((bh * cL + i) * cD);
        const vf4* xr4 = (const vf4*)(x + xoff);
        // W slice for lane k: 256 B contiguous
        const vf4* wr4 = (const vf4*)(Wt + ((size_t)h * cK + kc) * cD);

        float acc = 0.0f;
        #pragma unroll
        for (int d4 = 0; d4 < cD / 4; ++d4) {
            const vf4 xv = xr4[d4];
            const vf4 wv = wr4[d4];
            acc = fmaf(xv.x, wv.x, acc);
            acc = fmaf(xv.y, wv.y, acc);
            acc = fmaf(xv.z, wv.z, acc);
            acc = fmaf(xv.w, wv.w, acc);
        }

        // lt -> wave-private scratch (wave-synchronous, no barrier)
        sc[w][lane] = acc;
        const float* s = sc[w];

        // gather + 4 KB NT stores for this plane (r5's store walk)
        vf4* orow = (vf4*)(out + ((size_t)bh * cL + i) * cL);
        #pragma unroll
        for (int t = 0; t < 4; ++t) {
            const int4 bk = brow[t * 64 + lane];   // L1-hot after plane 0
            vf4 o;
            o.x = s[bk.x];
            o.y = s[bk.y];
            o.z = s[bk.z];
            o.w = s[bk.w];
            __builtin_nontemporal_store(o, &orow[t * 64 + lane]);
        }
    }
}

extern "C" void kernel_launch(void* const* d_in, const int* in_sizes, int n_in,
                              void* d_out, int out_size, void* d_ws, size_t ws_size,
                              hipStream_t stream) {
    const float* x      = (const float*)d_in[0];   // (8,8,1024,64) fp32
    const float* W      = (const float*)d_in[1];   // (8,64,49) fp32
    const int*   bucket = (const int*)d_in[2];     // (1024,1024) int32
    float*       out    = (float*)d_out;           // (8,8,1024,1024) fp32
    float*       Wt     = (float*)d_ws;            // (8,49,64) = 100 KB scratch

    transpose_w<<<8 * cK, cD, 0, stream>>>(W, Wt);
    irpe_fused<<<cL * 2, 256, 0, stream>>>(x, Wt, bucket, out);
}

// Round 10
// 302.775 us; speedup vs baseline: 1.1120x; 1.1120x over previous
//
#include <hip/hip_runtime.h>

// iRPE contextual/transposed PRODUCT:
//   lt[b,h,i,k] = sum_d x[b,h,i,d] * W[h,d,k]   (K=49 GEMV per row)
//   out[b,h,i,j] = lt[b,h,i, bucket[i,j]]        (the 256 MB write)
//
// FINAL (round-10): reversion to the round-5 kernel — the measured optimum
// (302.8 us). Structure: 2048 blocks (8/CU), block = one i x 32 bh planes;
// phase A stages x + bucket row, phase B GEMV -> LDS, phase C NT float4
// stores with the i-mod-8 CU swizzle. Five alternative structures (DRAM
// contiguity r3/r6, generation split r7, register-GEMV r8, per-plane
// fusion r9) all regressed 8-57 us; NT stores (r4, +9) and the channel
// swizzle (r5, +8) are the only levers that won. Remaining bench time is
// ~75% harness poison fills at the device's achievable write ceiling.

constexpr int cL = 1024;
constexpr int cD = 64;
constexpr int cK = 49;
constexpr int cHALF = 32; // bh rows per block

typedef float vf4 __attribute__((ext_vector_type(4)));

__global__ __launch_bounds__(256) void irpe_fused(
    const float* __restrict__ x,       // (B,H,L,D) = (bh, i, d)
    const float* __restrict__ W,       // (H,D,K)
    const int*   __restrict__ bucket,  // (L,L), values in [0,49)
    float*       __restrict__ out)     // (B,H,L,L)
{
    __shared__ vf4  xs4[cHALF][cD / 4];   // x[lh][d] as float4, 8 KB
    __shared__ float lts[cHALF * cK];     // lt values, 6.1 KB

    // ---- swizzled block -> (i, half) mapping ----
    // gid = i_lo*256 + i_hi*2 + half;  i = i_hi*8 + i_lo
    // Round-robin CU assignment (stride 256) walks i_lo through all 8
    // residues -> a CU's resident blocks cover all channel-bit groups.
    const int gid  = blockIdx.x;
    const int i_lo = gid >> 8;            // 0..7
    const int rest = gid & 255;
    const int i_hi = rest >> 1;           // 0..127
    const int half = gid & 1;
    const int i    = i_hi * 8 + i_lo;     // 0..1023
    const int bh0  = half * cHALF;
    const int tid  = threadIdx.x;

    // ---- Phase A: stage x rows (32 x 256 B, coalesced float4, nt loads) ----
    const vf4* x4 = (const vf4*)x;
    #pragma unroll
    for (int r = 0; r < 2; ++r) {
        const int idx = r * 256 + tid;
        const int lh  = idx >> 4;         // 0..31
        const int d4  = idx & 15;         // 0..15
        xs4[lh][d4] = __builtin_nontemporal_load(
            &x4[((size_t)(bh0 + lh) * cL + i) * (cD / 4) + d4]);
    }

    // bucket row i -> registers, reused for all 32 output rows (L2-cached;
    // the paired half-block with the same i shares it)
    const int4 bk = ((const int4*)(bucket + (size_t)i * cL))[tid];

    __syncthreads();

    // ---- Phase B: lts[lh*49+k] = sum_d xs[lh][d] * W[h,d,k] ----
    // Consecutive lanes -> consecutive k => coalesced W loads (L2-resident).
    const float* xsf = (const float*)xs4;
    for (int p = tid; p < cHALF * cK; p += 256) {
        const int lh = p / cK;
        const int k  = p - lh * cK;
        const int h  = (bh0 + lh) & 7;
        const float* wp = W + (size_t)h * cD * cK + k;
        const float* xr = xsf + lh * cD;
        float acc = 0.0f;
        #pragma unroll
        for (int d = 0; d < cD; ++d) {
            acc = fmaf(xr[d], wp[(size_t)d * cK], acc);
        }
        lts[p] = acc;
    }
    __syncthreads();

    // ---- Phase C: gather + stream 32 x 4 KB stores, NON-TEMPORAL ----
    vf4* obase = (vf4*)(out + ((size_t)bh0 * cL + i) * cL);
    #pragma unroll 4
    for (int lh = 0; lh < cHALF; ++lh) {
        const float* lrow = lts + lh * cK;
        vf4 o;
        o.x = lrow[bk.x];
        o.y = lrow[bk.y];
        o.z = lrow[bk.z];
        o.w = lrow[bk.w];
        __builtin_nontemporal_store(o, &obase[(size_t)lh * cL * (cL / 4) + tid]);
    }
}

extern "C" void kernel_launch(void* const* d_in, const int* in_sizes, int n_in,
                              void* d_out, int out_size, void* d_ws, size_t ws_size,
                              hipStream_t stream) {
    const float* x      = (const float*)d_in[0];   // (8,8,1024,64) fp32
    const float* W      = (const float*)d_in[1];   // (8,64,49) fp32
    const int*   bucket = (const int*)d_in[2];     // (1024,1024) int32
    float*       out    = (float*)d_out;           // (8,8,1024,1024) fp32

    const int grid = cL * 2;                        // 2048 blocks
    irpe_fused<<<grid, 256, 0, stream>>>(x, W, bucket, out);
}